// Round 5
// baseline (169.674 us; speedup 1.0000x reference)
//
#include <hip/hip_runtime.h>
#include <hip/hip_bf16.h>

#define HIDDEN 512
#define SEQ 256

typedef float f32x4 __attribute__((ext_vector_type(4)));

// One wave = one h. Lane = bl*16 + t (4 batches x 16 chunks). Each thread
// processes 4 chunks (4 different b), all 16 x-loads issued up front for MLP.
// W row is wave-uniform (readfirstlane) -> SGPRs via scalar loads, reused 4x.
// y stores are nontemporal so the 128 MiB y stream doesn't evict x from L3.
__device__ __forceinline__ float dot16(const f32x4& x0, const f32x4& x1,
                                       const f32x4& x2, const f32x4& x3,
                                       const f32x4& w0, const f32x4& w1,
                                       const f32x4& w2, const f32x4& w3) {
  float a;
  a = x0.x * w0.x;
  a = fmaf(x0.y, w0.y, a);
  a = fmaf(x0.z, w0.z, a);
  a = fmaf(x0.w, w0.w, a);
  a = fmaf(x1.x, w1.x, a);
  a = fmaf(x1.y, w1.y, a);
  a = fmaf(x1.z, w1.z, a);
  a = fmaf(x1.w, w1.w, a);
  a = fmaf(x2.x, w2.x, a);
  a = fmaf(x2.y, w2.y, a);
  a = fmaf(x2.z, w2.z, a);
  a = fmaf(x2.w, w2.w, a);
  a = fmaf(x3.x, w3.x, a);
  a = fmaf(x3.y, w3.y, a);
  a = fmaf(x3.z, w3.z, a);
  a = fmaf(x3.w, w3.w, a);
  return a;
}

__global__ __launch_bounds__(256) void LocalMixer_47579647705675_kernel(
    const float* __restrict__ x, const float* __restrict__ W,
    float* __restrict__ y) {
  const int tid  = threadIdx.x;
  const int wave = tid >> 6;
  const int lane = tid & 63;
  const int bl   = lane >> 4;  // batch-sub within wave (4)
  const int t    = lane & 15;  // chunk within row (16)

  const int blk    = blockIdx.x;
  const int b_tile = blk >> 7;   // 16 tiles of 16 b
  const int h_tile = blk & 127;  // 128 tiles of 4 h
  int h = h_tile * 4 + wave;
  h = __builtin_amdgcn_readfirstlane(h);  // force SGPR base for W

  const f32x4* Wp = reinterpret_cast<const f32x4*>(W + (size_t)h * 256);

  // Per-iteration row base: b = b_tile*16 + i*4 + bl
  size_t row[4];
#pragma unroll
  for (int i = 0; i < 4; ++i) {
    const int b = b_tile * 16 + i * 4 + bl;
    row[i] = ((size_t)b * HIDDEN + h) * SEQ + (size_t)t * 16;
  }

  // Issue all 16 x-loads up front (4 per iteration) for MLP.
  f32x4 xr[16];
#pragma unroll
  for (int i = 0; i < 4; ++i) {
    const f32x4* xp = reinterpret_cast<const f32x4*>(x + row[i]);
#pragma unroll
    for (int j = 0; j < 4; ++j) xr[i * 4 + j] = xp[j];
  }

#pragma unroll
  for (int i = 0; i < 4; ++i) {
    f32x4 out[4];
#pragma unroll
    for (int oq = 0; oq < 4; ++oq) {
      float acc[4];
#pragma unroll
      for (int oi = 0; oi < 4; ++oi) {
        const int o = oq * 4 + oi;
        const f32x4 w0 = Wp[4 * o + 0];
        const f32x4 w1 = Wp[4 * o + 1];
        const f32x4 w2 = Wp[4 * o + 2];
        const f32x4 w3 = Wp[4 * o + 3];
        acc[oi] = dot16(xr[i * 4 + 0], xr[i * 4 + 1], xr[i * 4 + 2],
                        xr[i * 4 + 3], w0, w1, w2, w3);
      }
      out[oq] = (f32x4){acc[0], acc[1], acc[2], acc[3]};
    }
    // Back-to-back contiguous nontemporal stores (64 B per lane).
    f32x4* yp = reinterpret_cast<f32x4*>(y + row[i]);
#pragma unroll
    for (int oq = 0; oq < 4; ++oq) __builtin_nontemporal_store(out[oq], yp + oq);
  }
}

extern "C" void kernel_launch(void* const* d_in, const int* in_sizes, int n_in,
                              void* d_out, int out_size, void* d_ws, size_t ws_size,
                              hipStream_t stream) {
  const float* x = (const float*)d_in[0];
  const float* W = (const float*)d_in[1];
  float* y = (float*)d_out;

  const int B = in_sizes[0] / (HIDDEN * SEQ);      // 256
  const int grid = (B / 16) * (HIDDEN / 4);        // 2048 blocks
  LocalMixer_47579647705675_kernel<<<grid, 256, 0, stream>>>(x, W, y);
}

// Round 6
// 84.985 us; speedup vs baseline: 1.9965x; 1.9965x over previous
//
#include <hip/hip_runtime.h>
#include <hip/hip_bf16.h>

#define HIDDEN 512
#define SEQ 256

typedef float f32x4 __attribute__((ext_vector_type(4)));

// One wave = one h. Lane = bl*16 + t (4 batches x 16 chunks). Each thread
// processes 4 chunks (4 different b), all 16 x-loads issued up front for MLP.
// W row is wave-uniform (readfirstlane) -> SGPRs via scalar loads, reused 4x.
// Plain (cached) stores: L2 write-combining is essential on CDNA4 —
// nontemporal stores regressed 59.8 -> 170 us (R5).
__device__ __forceinline__ float dot16(const f32x4& x0, const f32x4& x1,
                                       const f32x4& x2, const f32x4& x3,
                                       const f32x4& w0, const f32x4& w1,
                                       const f32x4& w2, const f32x4& w3) {
  float a;
  a = x0.x * w0.x;
  a = fmaf(x0.y, w0.y, a);
  a = fmaf(x0.z, w0.z, a);
  a = fmaf(x0.w, w0.w, a);
  a = fmaf(x1.x, w1.x, a);
  a = fmaf(x1.y, w1.y, a);
  a = fmaf(x1.z, w1.z, a);
  a = fmaf(x1.w, w1.w, a);
  a = fmaf(x2.x, w2.x, a);
  a = fmaf(x2.y, w2.y, a);
  a = fmaf(x2.z, w2.z, a);
  a = fmaf(x2.w, w2.w, a);
  a = fmaf(x3.x, w3.x, a);
  a = fmaf(x3.y, w3.y, a);
  a = fmaf(x3.z, w3.z, a);
  a = fmaf(x3.w, w3.w, a);
  return a;
}

__global__ __launch_bounds__(256) void LocalMixer_47579647705675_kernel(
    const float* __restrict__ x, const float* __restrict__ W,
    float* __restrict__ y) {
  const int tid  = threadIdx.x;
  const int wave = tid >> 6;
  const int lane = tid & 63;
  const int bl   = lane >> 4;  // batch-sub within wave (4)
  const int t    = lane & 15;  // chunk within row (16)

  const int blk    = blockIdx.x;
  const int b_tile = blk >> 7;   // 16 tiles of 16 b
  const int h_tile = blk & 127;  // 128 tiles of 4 h
  int h = h_tile * 4 + wave;
  h = __builtin_amdgcn_readfirstlane(h);  // force SGPR base for W

  const f32x4* Wp = reinterpret_cast<const f32x4*>(W + (size_t)h * 256);

  // Per-iteration row base: b = b_tile*16 + i*4 + bl
  size_t row[4];
#pragma unroll
  for (int i = 0; i < 4; ++i) {
    const int b = b_tile * 16 + i * 4 + bl;
    row[i] = ((size_t)b * HIDDEN + h) * SEQ + (size_t)t * 16;
  }

  // Issue all 16 x-loads up front (4 per iteration) for MLP.
  f32x4 xr[16];
#pragma unroll
  for (int i = 0; i < 4; ++i) {
    const f32x4* xp = reinterpret_cast<const f32x4*>(x + row[i]);
#pragma unroll
    for (int j = 0; j < 4; ++j) xr[i * 4 + j] = xp[j];
  }

#pragma unroll
  for (int i = 0; i < 4; ++i) {
    f32x4 out[4];
#pragma unroll
    for (int oq = 0; oq < 4; ++oq) {
      float acc[4];
#pragma unroll
      for (int oi = 0; oi < 4; ++oi) {
        const int o = oq * 4 + oi;
        const f32x4 w0 = Wp[4 * o + 0];
        const f32x4 w1 = Wp[4 * o + 1];
        const f32x4 w2 = Wp[4 * o + 2];
        const f32x4 w3 = Wp[4 * o + 3];
        acc[oi] = dot16(xr[i * 4 + 0], xr[i * 4 + 1], xr[i * 4 + 2],
                        xr[i * 4 + 3], w0, w1, w2, w3);
      }
      out[oq] = (f32x4){acc[0], acc[1], acc[2], acc[3]};
    }
    // Back-to-back contiguous cached stores (64 B per lane).
    f32x4* yp = reinterpret_cast<f32x4*>(y + row[i]);
#pragma unroll
    for (int oq = 0; oq < 4; ++oq) yp[oq] = out[oq];
  }
}

extern "C" void kernel_launch(void* const* d_in, const int* in_sizes, int n_in,
                              void* d_out, int out_size, void* d_ws, size_t ws_size,
                              hipStream_t stream) {
  const float* x = (const float*)d_in[0];
  const float* W = (const float*)d_in[1];
  float* y = (float*)d_out;

  const int B = in_sizes[0] / (HIDDEN * SEQ);      // 256
  const int grid = (B / 16) * (HIDDEN / 4);        // 2048 blocks
  LocalMixer_47579647705675_kernel<<<grid, 256, 0, stream>>>(x, W, y);
}